// Round 1
// baseline (353.921 us; speedup 1.0000x reference)
//
#include <hip/hip_runtime.h>
#include <cstdint>

#define B_SZ 8192
#define IN_SZ 1024
#define H_SZ 1024

typedef unsigned short u16;
typedef __bf16 bf16_t;
typedef bf16_t bf16x8 __attribute__((ext_vector_type(8)));
typedef float floatx4 __attribute__((ext_vector_type(4)));

__device__ __forceinline__ u16 f2bf(float f) {
    unsigned int u = __float_as_uint(f);
    u += 0x7fffu + ((u >> 16) & 1u);   // RNE
    return (u16)(u >> 16);
}

// async global->LDS, 16B per lane; LDS dest = wave-uniform base + lane*16
__device__ __forceinline__ void g2l16(const u16* g, u16* l) {
    __builtin_amdgcn_global_load_lds(
        (__attribute__((address_space(1))) void*)(uintptr_t)g,
        (__attribute__((address_space(3))) void*)(uint32_t)(uintptr_t)l,
        16, 0, 0);
}

// ---------------- fp32 -> bf16 conversion ----------------
__global__ __launch_bounds__(256) void cvt_kernel(const float* __restrict__ src,
                                                  u16* __restrict__ dst, int n4) {
    int i = blockIdx.x * 256 + threadIdx.x;
    if (i >= n4) return;
    float4 v = ((const float4*)src)[i];
    ushort4 o;
    o.x = f2bf(v.x); o.y = f2bf(v.y); o.z = f2bf(v.z); o.w = f2bf(v.w);
    ((ushort4*)dst)[i] = o;
}

__global__ __launch_bounds__(256) void cvt6_kernel(
    const float* __restrict__ s0, const float* __restrict__ s1,
    const float* __restrict__ s2, const float* __restrict__ s3,
    const float* __restrict__ s4, const float* __restrict__ s5,
    u16* __restrict__ d0, u16* __restrict__ d1, u16* __restrict__ d2,
    u16* __restrict__ d3, u16* __restrict__ d4, u16* __restrict__ d5) {
    const int w = blockIdx.x >> 10;                        // 1024 blocks / weight
    const int off = ((blockIdx.x & 1023) << 8) + threadIdx.x;  // float4 index
    const float* s; u16* d;
    switch (w) {
        case 0: s = s0; d = d0; break;
        case 1: s = s1; d = d1; break;
        case 2: s = s2; d = d2; break;
        case 3: s = s3; d = d3; break;
        case 4: s = s4; d = d4; break;
        default: s = s5; d = d5; break;
    }
    float4 v = ((const float4*)s)[off];
    ushort4 o;
    o.x = f2bf(v.x); o.y = f2bf(v.y); o.z = f2bf(v.z); o.w = f2bf(v.w);
    ((ushort4*)d)[off] = o;
}

// ---------------- fused two-segment NT GEMM + gate epilogue ----------------
// C[m,n] = sum_k A0[m,k]*B0[n,k] + sum_k A1[m,k]*B1[n,k]   (K=1024 per segment)
// MODE 0: r = sigmoid(C+bx+bh); out(bf16) = r*hidden
// MODE 1: out(f32) = sigmoid(C+bx+bh)            (z)
// MODE 2: ht = tanh(C+bx+bh); out(f32) = z*hidden + (1-z)*ht  (new_hidden)
template <int MODE>
__global__ __launch_bounds__(256) void gemm_gate(
    const u16* __restrict__ A0, const u16* __restrict__ B0,
    const u16* __restrict__ A1, const u16* __restrict__ B1,
    const float* __restrict__ bx, const float* __restrict__ bh,
    const float* __restrict__ hidden, const float* __restrict__ zbuf,
    void* __restrict__ outp) {
    constexpr int BM = 128, BN = 128, BK = 32, K = 1024;
    __shared__ u16 As[BM * BK];   // 8 KB, row-major [128][32], NO padding (global_load_lds)
    __shared__ u16 Bs[BN * BK];   // 8 KB
    const int tid = threadIdx.x;
    const int wave = tid >> 6;
    const int lane = tid & 63;
    const int bn = blockIdx.x, bm = blockIdx.y;
    const int wr = wave >> 1, wc = wave & 1;   // 2x2 wave grid, 64x64 per wave

    const floatx4 z4 = {0.f, 0.f, 0.f, 0.f};
    floatx4 acc[4][4];
#pragma unroll
    for (int i = 0; i < 4; ++i)
#pragma unroll
        for (int j = 0; j < 4; ++j) acc[i][j] = z4;

    const u16* Aseg[2] = {A0, A1};
    const u16* Bseg[2] = {B0, B1};

    for (int seg = 0; seg < 2; ++seg) {
        const u16* __restrict__ Ag = Aseg[seg];
        const u16* __restrict__ Bg = Bseg[seg];
        for (int kt = 0; kt < K / BK; ++kt) {
            const int k0 = kt * BK;
            // stage A and B tiles: 512 16B-chunks each; per wave 2 calls per tile
#pragma unroll
            for (int j = 0; j < 2; ++j) {
                const int c = j * 256 + wave * 64 + lane;  // chunk id 0..511
                const int row = c >> 2;
                const int s16 = c & 3;
                const int ldsc = (j * 256 + wave * 64) * 8;  // wave-uniform u16 index
                g2l16(Ag + (size_t)(bm * BM + row) * K + k0 + s16 * 8, &As[ldsc]);
                g2l16(Bg + (size_t)(bn * BN + row) * K + k0 + s16 * 8, &Bs[ldsc]);
            }
            __syncthreads();  // drains vmcnt: LDS tiles ready
            bf16x8 af[4], bfv[4];
            const int mr = lane & 15;
            const int q8 = (lane >> 4) * 8;
#pragma unroll
            for (int i = 0; i < 4; ++i)
                af[i] = *(const bf16x8*)&As[(wr * 64 + i * 16 + mr) * BK + q8];
#pragma unroll
            for (int j = 0; j < 4; ++j)
                bfv[j] = *(const bf16x8*)&Bs[(wc * 64 + j * 16 + mr) * BK + q8];
#pragma unroll
            for (int i = 0; i < 4; ++i)
#pragma unroll
                for (int j = 0; j < 4; ++j)
                    acc[i][j] = __builtin_amdgcn_mfma_f32_16x16x32_bf16(
                        af[i], bfv[j], acc[i][j], 0, 0, 0);
            __syncthreads();  // protect LDS before next stage overwrites
        }
    }

    // epilogue: C/D layout col=lane&15, row=(lane>>4)*4+reg (m89/m91 verified)
    const int colBase = bn * BN + wc * 64 + (lane & 15);
    const int rowBase = bm * BM + wr * 64 + (lane >> 4) * 4;
#pragma unroll
    for (int j = 0; j < 4; ++j) {
        const int coln = colBase + j * 16;
        const float bias = bx[coln] + bh[coln];
#pragma unroll
        for (int i = 0; i < 4; ++i) {
#pragma unroll
            for (int r = 0; r < 4; ++r) {
                const int rown = rowBase + i * 16 + r;
                const size_t idx = (size_t)rown * H_SZ + coln;
                const float v = acc[i][j][r] + bias;
                if constexpr (MODE == 0) {
                    const float rv = 1.0f / (1.0f + __expf(-v));
                    ((u16*)outp)[idx] = f2bf(rv * hidden[idx]);
                } else if constexpr (MODE == 1) {
                    ((float*)outp)[idx] = 1.0f / (1.0f + __expf(-v));
                } else {
                    const float ht = tanhf(v);
                    const float zz = zbuf[idx];
                    const float hh = hidden[idx];
                    ((float*)outp)[idx] = zz * hh + (1.0f - zz) * ht;
                }
            }
        }
    }
}

// ---------------- row-wise log_softmax over H=1024 ----------------
__global__ __launch_bounds__(256) void lsm_kernel(const float* __restrict__ nh,
                                                  float* __restrict__ out) {
    const int row = blockIdx.x;
    const int tid = threadIdx.x;
    const int wave = tid >> 6, lane = tid & 63;
    const float4 v = ((const float4*)(nh + (size_t)row * H_SZ))[tid];
    __shared__ float redm[4];
    __shared__ float reds[4];
    float m = fmaxf(fmaxf(v.x, v.y), fmaxf(v.z, v.w));
#pragma unroll
    for (int o = 32; o; o >>= 1) m = fmaxf(m, __shfl_xor(m, o));
    if (lane == 0) redm[wave] = m;
    __syncthreads();
    const float M = fmaxf(fmaxf(redm[0], redm[1]), fmaxf(redm[2], redm[3]));
    float s = __expf(v.x - M) + __expf(v.y - M) + __expf(v.z - M) + __expf(v.w - M);
#pragma unroll
    for (int o = 32; o; o >>= 1) s += __shfl_xor(s, o);
    if (lane == 0) reds[wave] = s;
    __syncthreads();
    const float S = reds[0] + reds[1] + reds[2] + reds[3];
    const float lse = M + __logf(S);
    float4 ov;
    ov.x = v.x - lse; ov.y = v.y - lse; ov.z = v.z - lse; ov.w = v.w - lse;
    ((float4*)(out + (size_t)row * H_SZ))[tid] = ov;
}

extern "C" void kernel_launch(void* const* d_in, const int* in_sizes, int n_in,
                              void* d_out, int out_size, void* d_ws, size_t ws_size,
                              hipStream_t stream) {
    const float* input  = (const float*)d_in[0];
    const float* hidden = (const float*)d_in[1];
    const float* Wir = (const float*)d_in[2];  const float* bir = (const float*)d_in[3];
    const float* Whr = (const float*)d_in[4];  const float* bhr = (const float*)d_in[5];
    const float* Wiz = (const float*)d_in[6];  const float* biz = (const float*)d_in[7];
    const float* Whz = (const float*)d_in[8];  const float* bhz = (const float*)d_in[9];
    const float* Wih = (const float*)d_in[10]; const float* bih = (const float*)d_in[11];
    const float* Whh = (const float*)d_in[12]; const float* bhh = (const float*)d_in[13];

    // workspace layout (92 MB total)
    char* ws = (char*)d_ws;
    u16* Xb  = (u16*)(ws);                      // 16 MB  input bf16
    u16* Hb  = (u16*)(ws + (16u << 20));        // 16 MB  hidden bf16
    u16* Wb0 = (u16*)(ws + (32u << 20));        // 2 MB each: Wir,Whr,Wiz,Whz,Wih,Whh
    u16* Wb1 = (u16*)(ws + (34u << 20));
    u16* Wb2 = (u16*)(ws + (36u << 20));
    u16* Wb3 = (u16*)(ws + (38u << 20));
    u16* Wb4 = (u16*)(ws + (40u << 20));
    u16* Wb5 = (u16*)(ws + (42u << 20));
    u16* RHb = (u16*)(ws + (44u << 20));        // 16 MB  r*hidden bf16
    float* Zf = (float*)(ws + (60u << 20));     // 32 MB  z f32

    float* out_lsm = (float*)d_out;
    float* out_nh  = (float*)d_out + (size_t)B_SZ * H_SZ;

    cvt_kernel<<<(B_SZ * IN_SZ / 4 + 255) / 256, 256, 0, stream>>>(input, Xb, B_SZ * IN_SZ / 4);
    cvt_kernel<<<(B_SZ * H_SZ / 4 + 255) / 256, 256, 0, stream>>>(hidden, Hb, B_SZ * H_SZ / 4);
    cvt6_kernel<<<6 * 1024, 256, 0, stream>>>(Wir, Whr, Wiz, Whz, Wih, Whh,
                                              Wb0, Wb1, Wb2, Wb3, Wb4, Wb5);

    dim3 g(H_SZ / 128, B_SZ / 128);  // (8, 64) = 512 blocks
    gemm_gate<0><<<g, 256, 0, stream>>>(Xb, Wb0, Hb, Wb1, bir, bhr, hidden, nullptr, RHb);
    gemm_gate<1><<<g, 256, 0, stream>>>(Xb, Wb2, Hb, Wb3, biz, bhz, hidden, nullptr, Zf);
    gemm_gate<2><<<g, 256, 0, stream>>>(Xb, Wb4, RHb, Wb5, bih, bhh, hidden, Zf, out_nh);
    lsm_kernel<<<B_SZ, 256, 0, stream>>>(out_nh, out_lsm);
}